// Round 9
// baseline (259.962 us; speedup 1.0000x reference)
//
#include <hip/hip_runtime.h>

// VQ-VAE quantizer — round 9: replicate the np/fp32 reference grid bit-exactly.
// Inputs fp32: z_e [32,64,64,64], codebook [512,64].
// Output fp32: z_q [8388608] ++ indices-as-float [131072].
//
// Reference (np, fp32): d = rn( rn(s1 + s2[k]) - 2*M32[k] ), argmin ties->lowest.
//   s1 = np.sum(z**2,axis=1):  square->round, pairwise-8 accumulators, no fma.
//   s2 = np.sum(cb**2,axis=1): same.
//   M32 = sgemm(z_flat, cb^T): sequential-k fmaf chain (OpenBLAS microkernel).
// R8 established: fp64-exact argmin != ref (absmax 490, ~10^2 grid-tie flips);
// the epilogue below is byte-identical to R8's (Output 0 passed).

typedef __attribute__((ext_vector_type(4))) float fl4;

__global__ __launch_bounds__(256)
void vq9(const float* __restrict__ z,
         const float* __restrict__ cb,
         float* __restrict__ out)
{
    __shared__ float s2l[512];
    __shared__ int   ifin[256];

    const int tid = threadIdx.x;
    const int n0  = blockIdx.x << 8;     // 512 blocks x 256 samples
    const int n   = n0 + tid;

    // ---- s2[k] = np.sum(cb[k]**2): square->round->add, pairwise-8, no fma ----
    for (int k = tid; k < 512; k += 256) {
        const float* row = cb + k * 64;
        float p[8];
        #pragma unroll
        for (int j = 0; j < 8; ++j) p[j] = __fmul_rn(row[j], row[j]);
        #pragma unroll
        for (int m = 1; m < 8; ++m)
            #pragma unroll
            for (int j = 0; j < 8; ++j)
                p[j] = __fadd_rn(p[j], __fmul_rn(row[m * 8 + j], row[m * 8 + j]));
        s2l[k] = __fadd_rn(__fadd_rn(__fadd_rn(p[0], p[1]), __fadd_rn(p[2], p[3])),
                           __fadd_rn(__fadd_rn(p[4], p[5]), __fadd_rn(p[6], p[7])));
    }
    __syncthreads();

    // ---- load sample n (coalesced: fixed c => consecutive tid, consecutive addr) ----
    // channel c of sample n: z[(n>>12)*262144 + c*4096 + (n&4095)]
    const size_t base = (size_t)(n >> 12) * 262144 + (size_t)(n & 4095);
    float zv[64];
    float p[8];
    #pragma unroll
    for (int c = 0; c < 64; ++c) {
        const float v = z[base + (size_t)c * 4096];
        zv[c] = v;
        const float sq = __fmul_rn(v, v);          // np: z**2 rounds first
        if (c < 8) p[c] = sq;                      // m = 0
        else       p[c & 7] = __fadd_rn(p[c & 7], sq);   // m ascending per j: np order
    }
    const float s1 = __fadd_rn(__fadd_rn(__fadd_rn(p[0], p[1]), __fadd_rn(p[2], p[3])),
                               __fadd_rn(__fadd_rn(p[4], p[5]), __fadd_rn(p[6], p[7])));

    // ---- argmin on the reference's fp32 grid ----
    // M32: sequential-k fmaf chain (BLAS microkernel order); d = rn(T - 2*M32).
    float best = 3.4e38f;
    int   bi   = 0;
    for (int k = 0; k < 512; ++k) {
        const float* row = cb + (size_t)k * 64;    // wave-uniform -> scalar loads
        float m32 = 0.0f;
        #pragma unroll
        for (int c = 0; c < 64; ++c)
            m32 = fmaf(row[c], zv[c], m32);        // single accumulator, k-sequential
        const float T = __fadd_rn(s1, s2l[k]);     // np: (s1+s2), one rounding
        const float d = __fsub_rn(T, 2.0f * m32);  // np: T - 2M  (2M exact)
        if (d < best) { best = d; bi = k; }        // strict <: lowest index wins ties
    }
    ifin[tid] = bi;
    out[8388608 + n] = (float)bi;                  // index as fp32 (exact)
    __syncthreads();

    // ---- z_q gather: exact fp32 copies, coalesced 16B stores (R8: passed) ----
    float* ob = out + (size_t)n0 * 64;
    #pragma unroll
    for (int it = 0; it < 16; ++it) {
        const int o    = it * 1024 + tid * 4;   // float offset in chunk [0, 16384)
        const int sloc = o >> 6;                // local sample
        const int c0   = o & 63;                // channel start (multiple of 4)
        const int idx  = ifin[sloc] & 511;      // defensive clamp
        const fl4 v = *(const fl4*)(cb + idx * 64 + c0);
        *(fl4*)(ob + o) = v;
    }
}

extern "C" void kernel_launch(void* const* d_in, const int* in_sizes, int n_in,
                              void* d_out, int out_size, void* d_ws, size_t ws_size,
                              hipStream_t stream) {
    const float* z  = (const float*)d_in[0];   // z_e fp32 [32,64,64,64]
    const float* cb = (const float*)d_in[1];   // codebook fp32 [512,64]
    float* out = (float*)d_out;                // fp32: z_q [8388608] ++ indices [131072]
    vq9<<<512, 256, 0, stream>>>(z, cb, out);
}